// Round 5
// baseline (268.277 us; speedup 1.0000x reference)
//
#include <hip/hip_runtime.h>

// Problem constants: B=4, S=4096, D=1024, H=64
#define NS 4       // attention key-range splits

typedef __attribute__((ext_vector_type(8))) short sh8;  // 8 x bf16 (4 VGPRs)
typedef __attribute__((ext_vector_type(4))) float f4;   // MFMA accumulator

// fold 1/sqrt(64) * log2(e) into Q so softmax is pure exp2
#define QSCALE 0.18033688011112042f

static __device__ __forceinline__ unsigned short f2bf(float f) {
  unsigned u = __builtin_bit_cast(unsigned, f);
  u += 0x7fffu + ((u >> 16) & 1u);   // RNE
  return (unsigned short)(u >> 16);
}
static __device__ __forceinline__ float bf2f(unsigned short s) {
  unsigned u = ((unsigned)s) << 16;
  return __builtin_bit_cast(float, u);
}

// ---------------- kernel 1: Wt[192][1024] bf16 = concat(Wq,Wk,Wv)^T ----------------
__global__ __launch_bounds__(256) void wt_kernel(const float* __restrict__ Wq,
                                                 const float* __restrict__ Wk,
                                                 const float* __restrict__ Wv,
                                                 unsigned short* __restrict__ Wt) {
  __shared__ float tile[64 * 65];
  int widx = blockIdx.x >> 4, kt = blockIdx.x & 15;
  const float* W = widx == 0 ? Wq : (widx == 1 ? Wk : Wv);
  int t = threadIdx.x;
  {
    int kl = t >> 2, seg = (t & 3) * 16;
    const float* src = W + (size_t)(kt * 64 + kl) * 64 + seg;
#pragma unroll
    for (int j = 0; j < 16; ++j) tile[kl * 65 + seg + j] = src[j];
  }
  __syncthreads();
  {
    int nl = t >> 2, ks = (t & 3) * 16;
    unsigned short* dst = Wt + (size_t)(widx * 64 + nl) * 1024 + kt * 64 + ks;
#pragma unroll
    for (int j = 0; j < 16; ++j) dst[j] = f2bf(tile[(ks + j) * 65 + nl]);
  }
}

// ---------------- kernel 2: barrier-free projection, B-in-registers ----------------
// Grid 2048 = (m-tile 0..1023) x (n-half 0..1). Block 512 thr = 8 waves; wave = k-eighth.
// Wave holds B frags (6 n-tiles x 4 k-steps = 24 sh8) in regs, streams A frags straight
// from global (16 rows x 128 B coalesced), 6 MFMAs per k-step. One barrier for k-reduce.
__global__ __launch_bounds__(512, 3) void proj_kernel(const float* __restrict__ in,
                                                      const unsigned short* __restrict__ Wt,
                                                      unsigned short* __restrict__ Qg,
                                                      unsigned short* __restrict__ Kg,
                                                      unsigned short* __restrict__ Vtg) {
  __shared__ float red[8 * 16 * 100];   // 51200 B: per-wave partials, pad 100 (bank shift)
  __shared__ float vtile[16 * 68];      // V transpose staging (nh==1 blocks only)
  int t = threadIdx.x;
  int w = t >> 6, lane = t & 63, quad = lane >> 4, l15 = lane & 15;
  int m0r = blockIdx.x >> 1, nh = blockIdx.x & 1;
  int m0 = m0r * 16;

  // B prologue: 24 independent global loads (L2-resident Wt)
  sh8 Bf[6][4];
  const unsigned short* bbase = Wt + (size_t)(nh * 96 + l15) * 1024 + w * 128 + quad * 8;
#pragma unroll
  for (int nt = 0; nt < 6; ++nt)
#pragma unroll
    for (int ks = 0; ks < 4; ++ks)
      Bf[nt][ks] = *(const sh8*)(bbase + (size_t)nt * 16384 + ks * 32);

  f4 acc[6];
  f4 z = {0.f, 0.f, 0.f, 0.f};
#pragma unroll
  for (int nt = 0; nt < 6; ++nt) acc[nt] = z;

  const float* abase = in + (size_t)(m0 + l15) * 1024 + w * 128 + quad * 8;
#pragma unroll
  for (int ks = 0; ks < 4; ++ks) {
    f4 lo = *(const f4*)(abase + ks * 32);
    f4 hi = *(const f4*)(abase + ks * 32 + 4);
    sh8 af;
#pragma unroll
    for (int j = 0; j < 4; ++j) {
      af[j] = (short)f2bf(lo[j]);
      af[4 + j] = (short)f2bf(hi[j]);
    }
#pragma unroll
    for (int nt = 0; nt < 6; ++nt)
      acc[nt] = __builtin_amdgcn_mfma_f32_16x16x32_bf16(af, Bf[nt][ks], acc[nt], 0, 0, 0);
  }

  // scatter partials (C-layout: row = quad*4+r, col = nt*16+l15)
#pragma unroll
  for (int nt = 0; nt < 6; ++nt)
#pragma unroll
    for (int r = 0; r < 4; ++r)
      red[w * 1600 + (quad * 4 + r) * 100 + nt * 16 + l15] = acc[nt][r];
  __syncthreads();

  // k-reduce: thread t handles row = t>>5 (0..15), cols c3..c3+2 (stride-3 -> conflict-free)
  int row = t >> 5, c3 = (t & 31) * 3;
  float v[3];
#pragma unroll
  for (int j = 0; j < 3; ++j) {
    float s = 0.f;
#pragma unroll
    for (int w8 = 0; w8 < 8; ++w8) s += red[w8 * 1600 + row * 100 + c3 + j];
    v[j] = s;
  }
  size_t grow = (size_t)m0 + row;
  if (nh == 0) {  // global cols 0..95: Q[0..63] + K[0..31]
#pragma unroll
    for (int j = 0; j < 3; ++j) {
      int c = c3 + j;
      if (c < 64) Qg[grow * 64 + c] = f2bf(v[j] * QSCALE);
      else        Kg[grow * 64 + (c - 64)] = f2bf(v[j]);
    }
  } else {        // global cols 96..191: K[32..63] + V[0..63]
#pragma unroll
    for (int j = 0; j < 3; ++j) {
      int c = c3 + j;
      if (c < 32) Kg[grow * 64 + 32 + c] = f2bf(v[j]);
      else        vtile[row * 68 + (c - 32)] = v[j];
    }
    __syncthreads();  // block-uniform branch (nh is per-block)
    int h = t >> 3, sl = (t & 7) * 2;
    int bb = m0 >> 12, s0 = m0 & 4095;
    unsigned short p0 = f2bf(vtile[sl * 68 + h]);
    unsigned short p1 = f2bf(vtile[(sl + 1) * 68 + h]);
    unsigned pack = (unsigned)p0 | ((unsigned)p1 << 16);
    *(unsigned*)&Vtg[(((size_t)(bb * 64 + h)) << 12) + s0 + sl] = pack;
  }
}

// ---------------- kernel 3: barrier-free causal flash attention, split-K ----------------
// grid (64*NS, B), 256 thr (4 waves). K/V fragments loaded straight from global
// (16 rows x 64 B coalesced, L1-shared across waves), register-prefetched one tile ahead.
// Only wave-private P LDS round-trip remains (lgkmcnt, no barrier).
__global__ __launch_bounds__(256, 3) void attn_split(const unsigned short* __restrict__ Qg,
                                                     const unsigned short* __restrict__ Kg,
                                                     const unsigned short* __restrict__ Vtg,
                                                     unsigned short* __restrict__ Opart,
                                                     float* __restrict__ Lpart) {
  __shared__ unsigned short Pw[4 * 16 * 72];
  int t = threadIdx.x;
  int b = blockIdx.y;
  int qt = 63 - (int)(blockIdx.x >> 2);  // heavy q-tiles first (LPT)
  int sp = blockIdx.x & 3;
  int wave = t >> 6, lane = t & 63, quad = lane >> 4, l15 = lane & 15;
  unsigned short* Pws = Pw + wave * 16 * 72;

  int qrow0 = qt * 64 + wave * 16;
  size_t pbase = ((size_t)sp * 4 + b) * 4096;

  int nkt = qt + 1;
  int chunk = (nkt + NS - 1) / NS;
  int t0 = sp * chunk, t1 = min(nkt, t0 + chunk);
  if (t0 >= t1) {  // empty chunk: zero partials
#pragma unroll
    for (int r = 0; r < 4; ++r) {
      size_t row = pbase + qrow0 + quad * 4 + r;
#pragma unroll
      for (int ht = 0; ht < 4; ++ht) Opart[row * 64 + ht * 16 + l15] = 0;
      if (l15 == 0) Lpart[row] = 0.f;
    }
    return;
  }

  sh8 qa[2];
#pragma unroll
  for (int ks = 0; ks < 2; ++ks)
    qa[ks] = *(const sh8*)&Qg[(size_t)((b << 12) + qrow0 + l15) * 64 + ks * 32 + quad * 8];

  sh8 ones;
#pragma unroll
  for (int j = 0; j < 8; ++j) ones[j] = (short)0x3F80;  // bf16 1.0

  f4 o[5];  // o[0..3]: O accumulator; o[4]: row-sum (P * ones)
  f4 z = {0.f, 0.f, 0.f, 0.f};
#pragma unroll
  for (int ht = 0; ht < 5; ++ht) o[ht] = z;

  // fragment global bases (i = ks*4 + nt):
  //   K frag: row = kt*64 + nt*16 + l15 (x64 elems), off = ks*32 + quad*8
  //   V frag: row = b*64 + nt*16 + l15 (x4096),      off = kt*64 + ks*32 + quad*8
  const unsigned short* Kb = Kg + ((size_t)(b << 12) + l15) * 64 + quad * 8;
  const unsigned short* Vb = Vtg + ((size_t)(b * 64 + l15)) * 4096 + quad * 8;

  sh8 kf[8], vf[8];
#pragma unroll
  for (int i = 0; i < 8; ++i) {
    int ks = i >> 2, nt = i & 3;
    kf[i] = *(const sh8*)(Kb + ((size_t)t0 * 64 + nt * 16) * 64 + ks * 32);
    vf[i] = *(const sh8*)(Vb + (size_t)nt * 16 * 4096 + t0 * 64 + ks * 32);
  }

  for (int kt = t0; kt < t1; ++kt) {
    f4 s[4];
#pragma unroll
    for (int nt = 0; nt < 4; ++nt) s[nt] = z;
#pragma unroll
    for (int ks = 0; ks < 2; ++ks)
#pragma unroll
      for (int nt = 0; nt < 4; ++nt)
        s[nt] = __builtin_amdgcn_mfma_f32_16x16x32_bf16(qa[ks], kf[ks * 4 + nt], s[nt], 0, 0, 0);

    // prefetch next K tile while softmax/PV run
    if (kt + 1 < t1) {
#pragma unroll
      for (int i = 0; i < 8; ++i) {
        int ks = i >> 2, nt = i & 3;
        kf[i] = *(const sh8*)(Kb + ((size_t)(kt + 1) * 64 + nt * 16) * 64 + ks * 32);
      }
    }

    if (kt == nkt - 1) {  // causal mask on the global diagonal tile
#pragma unroll
      for (int nt = 0; nt < 4; ++nt) {
        int key = kt * 64 + nt * 16 + l15;
#pragma unroll
        for (int r = 0; r < 4; ++r) {
          int row = qrow0 + quad * 4 + r;
          if (key > row) s[nt][r] = -__builtin_inff();
        }
      }
    }

    // static-max softmax: P = exp2(s); wave-private LDS round-trip (C-layout -> A-layout)
#pragma unroll
    for (int nt = 0; nt < 4; ++nt)
#pragma unroll
      for (int r = 0; r < 4; ++r)
        Pws[(quad * 4 + r) * 72 + nt * 16 + l15] = f2bf(exp2f(s[nt][r]));
    asm volatile("s_waitcnt lgkmcnt(0)" ::: "memory");

#pragma unroll
    for (int ks = 0; ks < 2; ++ks) {
      sh8 pa = *(const sh8*)&Pws[l15 * 72 + ks * 32 + quad * 8];
#pragma unroll
      for (int ht = 0; ht < 4; ++ht)
        o[ht] = __builtin_amdgcn_mfma_f32_16x16x32_bf16(pa, vf[ks * 4 + ht], o[ht], 0, 0, 0);
      o[4] = __builtin_amdgcn_mfma_f32_16x16x32_bf16(pa, ones, o[4], 0, 0, 0);
    }

    // prefetch next V tile
    if (kt + 1 < t1) {
#pragma unroll
      for (int i = 0; i < 8; ++i) {
        int ks = i >> 2, nt = i & 3;
        vf[i] = *(const sh8*)(Vb + (size_t)nt * 16 * 4096 + (kt + 1) * 64 + ks * 32);
      }
    }
  }

  // write partials (unnormalized O, bf16; L fp32)
#pragma unroll
  for (int r = 0; r < 4; ++r) {
    size_t row = pbase + qrow0 + quad * 4 + r;
#pragma unroll
    for (int ht = 0; ht < 4; ++ht)
      Opart[row * 64 + ht * 16 + l15] = f2bf(o[ht][r]);
    if (l15 == 0) Lpart[row] = o[4][r];
  }
}

// ---------------- kernel 4: combine split partials ----------------
__global__ __launch_bounds__(256) void attn_combine(const unsigned short* __restrict__ Opart,
                                                    const float* __restrict__ Lpart,
                                                    float* __restrict__ out) {
  int t = threadIdx.x;
  int rg = blockIdx.x * 4 + (t >> 6);  // global row 0..16383
  int lane = t & 63;
  float acc = 0.f, L = 0.f;
#pragma unroll
  for (int s = 0; s < NS; ++s) {
    L += Lpart[(size_t)s * 16384 + rg];
    acc += bf2f(Opart[((size_t)s * 16384 + rg) * 64 + lane]);
  }
  out[(size_t)rg * 64 + lane] = acc / L;
}

extern "C" void kernel_launch(void* const* d_in, const int* in_sizes, int n_in,
                              void* d_out, int out_size, void* d_ws, size_t ws_size,
                              hipStream_t stream) {
  const float* in = (const float*)d_in[0];
  const float* Wq = (const float*)d_in[1];
  const float* Wk = (const float*)d_in[2];
  const float* Wv = (const float*)d_in[3];
  float* out = (float*)d_out;

  char* ws = (char*)d_ws;
  unsigned short* Wt    = (unsigned short*)ws;                 // 393,216 B
  unsigned short* Qg    = (unsigned short*)(ws + 393216);      // 2 MiB
  unsigned short* Kg    = (unsigned short*)(ws + 2490368);     // 2 MiB
  unsigned short* Vtg   = (unsigned short*)(ws + 4587520);     // 2 MiB
  unsigned short* Opart = (unsigned short*)(ws + 6684672);     // 8,388,608 B
  float*          Lpart = (float*)(ws + 15073280);             // 262,144 B

  hipLaunchKernelGGL(wt_kernel, dim3(48), dim3(256), 0, stream, Wq, Wk, Wv, Wt);
  hipLaunchKernelGGL(proj_kernel, dim3(2048), dim3(512), 0, stream, in, Wt, Qg, Kg, Vtg);
  hipLaunchKernelGGL(attn_split, dim3(64 * NS, 4), dim3(256), 0, stream,
                     Qg, Kg, Vtg, Opart, Lpart);
  hipLaunchKernelGGL(attn_combine, dim3(4096), dim3(256), 0, stream,
                     Opart, Lpart, out);
}

// Round 6
// 189.936 us; speedup vs baseline: 1.4125x; 1.4125x over previous
//
#include <hip/hip_runtime.h>

// Problem constants: B=4, S=4096, D=1024, H=64
#define NS 4       // attention key-range splits

typedef __attribute__((ext_vector_type(8))) short sh8;  // 8 x bf16 (4 VGPRs)
typedef __attribute__((ext_vector_type(4))) short sh4;  // 4 x bf16 (8 B)
typedef __attribute__((ext_vector_type(4))) float f4;   // MFMA accumulator

// fold 1/sqrt(64) * log2(e) into Q so softmax is pure exp2
#define QSCALE 0.18033688011112042f

typedef const __attribute__((address_space(1))) unsigned int* gas_t;
typedef __attribute__((address_space(3))) unsigned int* las_t;
#define GLD16(g, l) __builtin_amdgcn_global_load_lds((gas_t)(g), (las_t)(l), 16, 0, 0)

static __device__ __forceinline__ unsigned short f2bf(float f) {
  unsigned u = __builtin_bit_cast(unsigned, f);
  u += 0x7fffu + ((u >> 16) & 1u);   // RNE
  return (unsigned short)(u >> 16);
}
static __device__ __forceinline__ float bf2f(unsigned short s) {
  unsigned u = ((unsigned)s) << 16;
  return __builtin_bit_cast(float, u);
}

// ---------------- kernel 1: Wt[192][1024] bf16 = concat(Wq,Wk,Wv)^T ----------------
__global__ __launch_bounds__(256) void wt_kernel(const float* __restrict__ Wq,
                                                 const float* __restrict__ Wk,
                                                 const float* __restrict__ Wv,
                                                 unsigned short* __restrict__ Wt) {
  __shared__ float tile[64 * 65];
  int widx = blockIdx.x >> 4, kt = blockIdx.x & 15;
  const float* W = widx == 0 ? Wq : (widx == 1 ? Wk : Wv);
  int t = threadIdx.x;
  {
    int kl = t >> 2, seg = (t & 3) * 16;
    const float* src = W + (size_t)(kt * 64 + kl) * 64 + seg;
#pragma unroll
    for (int j = 0; j < 16; ++j) tile[kl * 65 + seg + j] = src[j];
  }
  __syncthreads();
  {
    int nl = t >> 2, ks = (t & 3) * 16;
    unsigned short* dst = Wt + (size_t)(widx * 64 + nl) * 1024 + kt * 64 + ks;
#pragma unroll
    for (int j = 0; j < 16; ++j) dst[j] = f2bf(tile[(ks + j) * 65 + nl]);
  }
}

// ---------------- kernel 2: projection, glds pipeline, M=16 tile, 4 blocks/CU ----------------
// 1024 blocks x 256 threads (4 waves). Tile M=16, N=192, k-step 32, 32 iters.
// Per buffer: A 2x1KB fp32 chunks + B 12x1KB bf16 chunks = 14 KB; double-buffered (28 KB).
// Chunk = one wave glds16 arranged so ds_read at chunk_base + lane*16 IS the MFMA fragment.
__global__ __launch_bounds__(256, 4) void proj_kernel(const float* __restrict__ in,
                                                      const unsigned short* __restrict__ Wt,
                                                      unsigned short* __restrict__ Qg,
                                                      unsigned short* __restrict__ Kg,
                                                      unsigned short* __restrict__ Vtg) {
  __shared__ __align__(16) char lds[28672];   // 2 x 14336
  int t = threadIdx.x;
  int w = t >> 6, lane = t & 63, quad = lane >> 4, l15 = lane & 15;
  int m0 = blockIdx.x * 16;

  // staging bases: A chunk c(0,1): lane l -> in[(m0+l15)*1024 + k0 + quad*8 + c*4 ..+3]
  //                B chunk c(2..13): nt=c-2, lane l -> Wt[(nt*16+l15)*1024 + k0 + quad*8 ..+7]
  const float* gA = in + (size_t)(m0 + l15) * 1024 + quad * 8;
  const unsigned short* gB = Wt + (size_t)l15 * 1024 + quad * 8;

  f4 acc[3];
  f4 z = {0.f, 0.f, 0.f, 0.f};
#pragma unroll
  for (int j = 0; j < 3; ++j) acc[j] = z;

#define STAGE(kt, buf)                                                         \
  {                                                                            \
    int k0 = (kt) * 32;                                                        \
    char* base = lds + (buf) * 14336;                                          \
    _Pragma("unroll")                                                          \
    for (int i = 0; i < 4; ++i) {                                              \
      int c = w + i * 4;                                                       \
      if (c < 14) {                                                            \
        if (c < 2) GLD16(gA + k0 + c * 4, base + c * 1024);                    \
        else GLD16(gB + (size_t)(c - 2) * 16384 + k0, base + c * 1024);        \
      }                                                                        \
    }                                                                          \
  }

  STAGE(0, 0);
  for (int kt = 0; kt < 32; ++kt) {
    int cur = kt & 1;
    __syncthreads();                      // buf[cur] staged (vmcnt drained), prev reads done
    if (kt + 1 < 32) STAGE(kt + 1, cur ^ 1);

    const f4* Af = (const f4*)(lds + cur * 14336);
    f4 lo = Af[lane], hi = Af[64 + lane];
    sh8 af;
#pragma unroll
    for (int j = 0; j < 4; ++j) {
      af[j] = (short)f2bf(lo[j]);
      af[4 + j] = (short)f2bf(hi[j]);
    }
    const sh8* Bf = (const sh8*)(lds + cur * 14336 + 2048);
#pragma unroll
    for (int j = 0; j < 3; ++j) {
      sh8 bf = Bf[(w * 3 + j) * 64 + lane];
      acc[j] = __builtin_amdgcn_mfma_f32_16x16x32_bf16(af, bf, acc[j], 0, 0, 0);
    }
  }
#undef STAGE

  // epilogue: wave w owns bands w*3..w*3+2 (16 cols each): 0-3 Q, 4-7 K, 8-11 V
  float* vtile = (float*)lds;   // [16][68] fp32, aliases buf0 (last compute read buf1)
#pragma unroll
  for (int j = 0; j < 3; ++j) {
    int band = w * 3 + j;
#pragma unroll
    for (int r = 0; r < 4; ++r) {
      int row = quad * 4 + r;
      float v = acc[j][r];
      if (band < 4) {
        Qg[(size_t)(m0 + row) * 64 + band * 16 + l15] = f2bf(v * QSCALE);
      } else if (band < 8) {
        Kg[(size_t)(m0 + row) * 64 + (band - 4) * 16 + l15] = f2bf(v);
      } else {
        vtile[row * 68 + (band - 8) * 16 + l15] = v;
      }
    }
  }
  __syncthreads();
  {
    int h = t >> 2, sl = (t & 3) * 4;
    int bb = m0 >> 12, s0 = m0 & 4095;
    sh4 vv;
#pragma unroll
    for (int j = 0; j < 4; ++j) vv[j] = (short)f2bf(vtile[(sl + j) * 68 + h]);
    *(sh4*)&Vtg[(((size_t)(bb * 64 + h)) << 12) + s0 + sl] = vv;
  }
}

// ---------------- kernel 3: causal flash attention, static-max softmax, split-K ----------------
// grid (64*NS, B), 256 threads (4 waves). Block = q-tile of 64 rows x key-chunk.
// K/V tiles register-prefetched across the barrier to hide global latency. (R4 version.)
__global__ __launch_bounds__(256, 4) void attn_split(const unsigned short* __restrict__ Qg,
                                                     const unsigned short* __restrict__ Kg,
                                                     const unsigned short* __restrict__ Vtg,
                                                     unsigned short* __restrict__ Opart,
                                                     float* __restrict__ Lpart) {
  __shared__ unsigned short Ks[64 * 72];
  __shared__ unsigned short Vs[64 * 72];
  __shared__ unsigned short Pw[4 * 16 * 72];
  int t = threadIdx.x;
  int b = blockIdx.y;
  int qt = 63 - (int)(blockIdx.x >> 2);  // heavy q-tiles first (LPT)
  int sp = blockIdx.x & 3;
  int wave = t >> 6, lane = t & 63, quad = lane >> 4, l15 = lane & 15;
  unsigned short* Pws = Pw + wave * 16 * 72;

  int qrow0 = qt * 64 + wave * 16;
  size_t pbase = ((size_t)sp * 4 + b) * 4096;

  int nkt = qt + 1;
  int chunk = (nkt + NS - 1) / NS;
  int t0 = sp * chunk, t1 = min(nkt, t0 + chunk);
  if (t0 >= t1) {  // empty chunk: zero partials
#pragma unroll
    for (int r = 0; r < 4; ++r) {
      size_t row = pbase + qrow0 + quad * 4 + r;
#pragma unroll
      for (int ht = 0; ht < 4; ++ht) Opart[row * 64 + ht * 16 + l15] = 0;
      if (l15 == 0) Lpart[row] = 0.f;
    }
    return;
  }

  sh8 qa[2];
#pragma unroll
  for (int ks = 0; ks < 2; ++ks)
    qa[ks] = *(const sh8*)&Qg[(size_t)((b << 12) + qrow0 + l15) * 64 + ks * 32 + quad * 8];

  sh8 ones;
#pragma unroll
  for (int j = 0; j < 8; ++j) ones[j] = (short)0x3F80;  // bf16 1.0

  f4 o[5];  // o[0..3]: O accumulator; o[4]: row-sum (P * ones)
  f4 z = {0.f, 0.f, 0.f, 0.f};
#pragma unroll
  for (int ht = 0; ht < 5; ++ht) o[ht] = z;

  // staging geometry: thread covers chunks c0=t, c1=t+256; row=c>>3, off=(c&7)*8
  int r0 = t >> 3, o0 = (t & 7) * 8;
  int r1 = (t + 256) >> 3, o1 = ((t + 256) & 7) * 8;
  const unsigned short* kg0 = Kg + (size_t)((b << 12) + r0) * 64 + o0;
  const unsigned short* kg1 = Kg + (size_t)((b << 12) + r1) * 64 + o1;
  const unsigned short* vg0 = Vtg + (((size_t)(b * 64 + r0)) << 12) + o0;
  const unsigned short* vg1 = Vtg + (((size_t)(b * 64 + r1)) << 12) + o1;

  sh8 kr0, kr1, vr0, vr1;
  {
    size_t ko = (size_t)t0 * 64 * 64;
    kr0 = *(const sh8*)(kg0 + ko); kr1 = *(const sh8*)(kg1 + ko);
    vr0 = *(const sh8*)(vg0 + t0 * 64); vr1 = *(const sh8*)(vg1 + t0 * 64);
  }

  for (int kt = t0; kt < t1; ++kt) {
    __syncthreads();                      // prev-iter LDS reads done
    *(sh8*)&Ks[r0 * 72 + o0] = kr0;
    *(sh8*)&Ks[r1 * 72 + o1] = kr1;
    *(sh8*)&Vs[r0 * 72 + o0] = vr0;
    *(sh8*)&Vs[r1 * 72 + o1] = vr1;
    if (kt + 1 < t1) {                    // prefetch next tile into regs
      size_t ko = (size_t)(kt + 1) * 64 * 64;
      kr0 = *(const sh8*)(kg0 + ko); kr1 = *(const sh8*)(kg1 + ko);
      vr0 = *(const sh8*)(vg0 + (kt + 1) * 64); vr1 = *(const sh8*)(vg1 + (kt + 1) * 64);
    }
    __syncthreads();                      // Ks/Vs visible

    f4 s[4];
#pragma unroll
    for (int nt = 0; nt < 4; ++nt) s[nt] = z;
#pragma unroll
    for (int ks = 0; ks < 2; ++ks) {
#pragma unroll
      for (int nt = 0; nt < 4; ++nt) {
        sh8 kb = *(const sh8*)&Ks[(nt * 16 + l15) * 72 + ks * 32 + quad * 8];
        s[nt] = __builtin_amdgcn_mfma_f32_16x16x32_bf16(qa[ks], kb, s[nt], 0, 0, 0);
      }
    }

    if (kt == nkt - 1) {  // causal mask on the global diagonal tile
#pragma unroll
      for (int nt = 0; nt < 4; ++nt) {
        int key = kt * 64 + nt * 16 + l15;
#pragma unroll
        for (int r = 0; r < 4; ++r) {
          int row = qrow0 + quad * 4 + r;
          if (key > row) s[nt][r] = -__builtin_inff();
        }
      }
    }

    // static-max softmax: P = exp2(s); wave-private LDS round-trip (C-layout -> A-layout)
#pragma unroll
    for (int nt = 0; nt < 4; ++nt)
#pragma unroll
      for (int r = 0; r < 4; ++r)
        Pws[(quad * 4 + r) * 72 + nt * 16 + l15] = f2bf(exp2f(s[nt][r]));
    asm volatile("s_waitcnt lgkmcnt(0)" ::: "memory");

#pragma unroll
    for (int ks = 0; ks < 2; ++ks) {
      sh8 pa = *(const sh8*)&Pws[l15 * 72 + ks * 32 + quad * 8];
#pragma unroll
      for (int ht = 0; ht < 4; ++ht) {
        sh8 vb = *(const sh8*)&Vs[(ht * 16 + l15) * 72 + ks * 32 + quad * 8];
        o[ht] = __builtin_amdgcn_mfma_f32_16x16x32_bf16(pa, vb, o[ht], 0, 0, 0);
      }
      o[4] = __builtin_amdgcn_mfma_f32_16x16x32_bf16(pa, ones, o[4], 0, 0, 0);
    }
  }

  // write partials (unnormalized O, bf16; L fp32)
#pragma unroll
  for (int r = 0; r < 4; ++r) {
    size_t row = pbase + qrow0 + quad * 4 + r;
#pragma unroll
    for (int ht = 0; ht < 4; ++ht)
      Opart[row * 64 + ht * 16 + l15] = f2bf(o[ht][r]);
    if (l15 == 0) Lpart[row] = o[4][r];
  }
}

// ---------------- kernel 4: combine split partials ----------------
__global__ __launch_bounds__(256) void attn_combine(const unsigned short* __restrict__ Opart,
                                                    const float* __restrict__ Lpart,
                                                    float* __restrict__ out) {
  int t = threadIdx.x;
  int rg = blockIdx.x * 4 + (t >> 6);  // global row 0..16383
  int lane = t & 63;
  float acc = 0.f, L = 0.f;
#pragma unroll
  for (int s = 0; s < NS; ++s) {
    L += Lpart[(size_t)s * 16384 + rg];
    acc += bf2f(Opart[((size_t)s * 16384 + rg) * 64 + lane]);
  }
  out[(size_t)rg * 64 + lane] = acc / L;
}

extern "C" void kernel_launch(void* const* d_in, const int* in_sizes, int n_in,
                              void* d_out, int out_size, void* d_ws, size_t ws_size,
                              hipStream_t stream) {
  const float* in = (const float*)d_in[0];
  const float* Wq = (const float*)d_in[1];
  const float* Wk = (const float*)d_in[2];
  const float* Wv = (const float*)d_in[3];
  float* out = (float*)d_out;

  char* ws = (char*)d_ws;
  unsigned short* Wt    = (unsigned short*)ws;                 // 393,216 B
  unsigned short* Qg    = (unsigned short*)(ws + 393216);      // 2 MiB
  unsigned short* Kg    = (unsigned short*)(ws + 2490368);     // 2 MiB
  unsigned short* Vtg   = (unsigned short*)(ws + 4587520);     // 2 MiB
  unsigned short* Opart = (unsigned short*)(ws + 6684672);     // 8,388,608 B
  float*          Lpart = (float*)(ws + 15073280);             // 262,144 B

  hipLaunchKernelGGL(wt_kernel, dim3(48), dim3(256), 0, stream, Wq, Wk, Wv, Wt);
  hipLaunchKernelGGL(proj_kernel, dim3(1024), dim3(256), 0, stream, in, Wt, Qg, Kg, Vtg);
  hipLaunchKernelGGL(attn_split, dim3(64 * NS, 4), dim3(256), 0, stream,
                     Qg, Kg, Vtg, Opart, Lpart);
  hipLaunchKernelGGL(attn_combine, dim3(4096), dim3(256), 0, stream,
                     Opart, Lpart, out);
}